// Round 8
// baseline (356.859 us; speedup 1.0000x reference)
//
#include <hip/hip_runtime.h>
#include <hip/hip_bf16.h>

#define H 128
#define BSH 8              // 256 nodes per coarse bucket
#define MAXB 1024          // max buckets (nTot <= 262144)

typedef __attribute__((ext_vector_type(8))) short short8;
typedef __attribute__((ext_vector_type(4))) short short4v;
typedef __attribute__((ext_vector_type(4))) float floatx4;
typedef unsigned short ushort_t;
typedef unsigned int uint_t;

__device__ __forceinline__ short f2bf(float f) {
    __hip_bfloat16 h = __float2bfloat16(f);
    return *reinterpret_cast<short*>(&h);
}
__device__ __forceinline__ float bflo(uint_t u) { return __uint_as_float(u << 16); }
__device__ __forceinline__ float bfhi(uint_t u) { return __uint_as_float(u & 0xFFFF0000u); }
__device__ __forceinline__ uint_t pack_bf2(float x, float y) {
    return (uint_t)(ushort_t)f2bf(x) | ((uint_t)(ushort_t)f2bf(y) << 16);
}

// ===========================================================================
// Coarse bucket histogram (LDS) + fused fp32->bf16 converts (emb + weights).
// ===========================================================================
__global__ __launch_bounds__(256)
void bucket_hist_cvt_kernel(const int* __restrict__ ei1, const int* __restrict__ ei2,
                            int E, int NF, int B, int* __restrict__ bcnt, int nbh,
                            const float* __restrict__ a, int n4a,
                            const float* __restrict__ b, int n4b,
                            ushort_t* __restrict__ da, ushort_t* __restrict__ db,
                            const float* __restrict__ Wl_cf, const float* __restrict__ Wr_cf,
                            const float* __restrict__ Wl_fc, const float* __restrict__ Wr_fc,
                            const float* __restrict__ W1, ushort_t* __restrict__ wb) {
    __shared__ int h[MAXB];
    int tid = threadIdx.x;
    if ((int)blockIdx.x < nbh) {
        for (int i = tid; i < B; i += 256) h[i] = 0;
        __syncthreads();
        int base = blockIdx.x * 4096;
        #pragma unroll 4
        for (int it = 0; it < 16; ++it) {
            int t = base + it * 256 + tid;
            if (t < 2 * E) {
                int g = (t < E) ? ei1[E + t] : (ei2[E + t - E] + NF);
                atomicAdd(&h[g >> BSH], 1);
            }
        }
        __syncthreads();
        for (int i = tid; i < B; i += 256)
            if (h[i]) atomicAdd(&bcnt[i], h[i]);
        return;
    }
    // ---- cvt part ----
    int i = ((int)blockIdx.x - nbh) * 256 + tid;
    const float* src; ushort_t* dst; int k;
    if (i < n4a) { src = a; dst = da; k = i; }
    else if (i < n4a + n4b) { src = b; dst = db; k = i - n4a; }
    else {
        int idx = (i - n4a - n4b) * 4;
        if (idx >= 98304) return;
        int off;
        if      (idx < 16384) { src = Wl_cf; off = idx; }
        else if (idx < 32768) { src = Wr_cf; off = idx - 16384; }
        else if (idx < 49152) { src = Wl_fc; off = idx - 32768; }
        else if (idx < 65536) { src = Wr_fc; off = idx - 49152; }
        else                  { src = W1;    off = idx - 65536; }
        float4 v = *(const float4*)(src + off);
        short4v s;
        s[0] = f2bf(v.x); s[1] = f2bf(v.y); s[2] = f2bf(v.z); s[3] = f2bf(v.w);
        *(short4v*)(wb + idx) = s;
        return;
    }
    float4 v = ((const float4*)src)[k];
    short4v s;
    s[0] = f2bf(v.x); s[1] = f2bf(v.y); s[2] = f2bf(v.z); s[3] = f2bf(v.w);
    ((short4v*)dst)[k] = s;
}

// ===========================================================================
// Exclusive scan of bucket counts (single block).
// ===========================================================================
__global__ __launch_bounds__(256)
void bucket_scan_kernel(const int* __restrict__ bcnt, int B,
                        int* __restrict__ bbase, int* __restrict__ bfront) {
    __shared__ int sdata[256];
    int tid = threadIdx.x;
    int base = tid * 4;
    int v[4]; int s = 0;
    #pragma unroll
    for (int i = 0; i < 4; ++i) { int idx = base + i; v[i] = (idx < B) ? bcnt[idx] : 0; s += v[i]; }
    sdata[tid] = s;
    __syncthreads();
    for (int off = 1; off < 256; off <<= 1) {
        int t = (tid >= off) ? sdata[tid - off] : 0;
        __syncthreads();
        sdata[tid] += t;
        __syncthreads();
    }
    int excl = tid ? sdata[tid - 1] : 0;
    #pragma unroll
    for (int i = 0; i < 4; ++i) {
        int idx = base + i;
        if (idx < B) { bbase[idx] = excl; bfront[idx] = excl; }
        excl += v[i];
    }
    if (tid == 255) bbase[B] = excl;
}

// ===========================================================================
// Partition edges into bucket-sorted (src,g) pairs (line-local writes).
// ===========================================================================
__global__ __launch_bounds__(256)
void partition_kernel(const int* __restrict__ ei1, const int* __restrict__ ei2,
                      int E, int NF, int B,
                      int* __restrict__ bfront, uint2* __restrict__ part) {
    __shared__ int h[MAXB];
    __shared__ int basex[MAXB];
    int tid = threadIdx.x;
    for (int i = tid; i < B; i += 256) h[i] = 0;
    __syncthreads();
    int base = blockIdx.x * 4096;
    #pragma unroll 4
    for (int it = 0; it < 16; ++it) {
        int t = base + it * 256 + tid;
        if (t < 2 * E) {
            int g = (t < E) ? ei1[E + t] : (ei2[E + t - E] + NF);
            atomicAdd(&h[g >> BSH], 1);
        }
    }
    __syncthreads();
    for (int i = tid; i < B; i += 256) {
        int c = h[i];
        basex[i] = c ? atomicAdd(&bfront[i], c) : 0;
    }
    __syncthreads();
    for (int i = tid; i < B; i += 256) h[i] = 0;
    __syncthreads();
    #pragma unroll 4
    for (int it = 0; it < 16; ++it) {
        int t = base + it * 256 + tid;
        if (t < 2 * E) {
            int g, s;
            if (t < E) { g = ei1[E + t]; s = ei1[t]; }
            else       { int e = t - E; g = ei2[E + e] + NF; s = ei2[e]; }
            int bk = g >> BSH;
            int r = atomicAdd(&h[bk], 1);
            part[basex[bk] + r] = make_uint2((uint_t)s, (uint_t)g);
        }
    }
}

// ===========================================================================
// Fine bin: one block per bucket -> CSR start offsets + line-local bins.
// ===========================================================================
__global__ __launch_bounds__(256)
void fine_bin_kernel(const int* __restrict__ bbase, int nTot,
                     const uint2* __restrict__ part,
                     int* __restrict__ offs, int* __restrict__ bins) {
    __shared__ int cnt[256];
    __shared__ int sdata[256];
    __shared__ int excl[256];
    int b = blockIdx.x;
    int tid = threadIdx.x;
    int seg0 = bbase[b], seg1 = bbase[b + 1];
    int gbase = b << BSH;
    cnt[tid] = 0;
    __syncthreads();
    for (int k = seg0 + tid; k < seg1; k += 256)
        atomicAdd(&cnt[part[k].y - gbase], 1);
    __syncthreads();
    sdata[tid] = cnt[tid];
    __syncthreads();
    for (int off = 1; off < 256; off <<= 1) {
        int t = (tid >= off) ? sdata[tid - off] : 0;
        __syncthreads();
        sdata[tid] += t;
        __syncthreads();
    }
    excl[tid] = tid ? sdata[tid - 1] : 0;
    int g = gbase + tid;
    if (g < nTot) offs[g] = seg0 + excl[tid];
    if (b == (int)gridDim.x - 1 && tid == 0) offs[nTot] = seg1;
    cnt[tid] = 0;
    __syncthreads();
    for (int k = seg0 + tid; k < seg1; k += 256) {
        uint2 e = part[k];
        int l = (int)e.y - gbase;
        int r = atomicAdd(&cnt[l], 1);
        bins[seg0 + excl[l] + r] = (int)e.x;
    }
}

// ===========================================================================
// FUSED gather-mean + SAGE MFMA + first-MLP projection.
// Block = 64 dst rows. Phase A: each wave gathers 16 nodes' means straight
// into LDS A[.. ][0..127] (quarter q x uint4 -> 1 load = 4 edges' rows).
// Phase B: stage self-emb into A[..][128..255]. Then GEMM1(K=256) -> relu
// -> GEMM2(K=128) -> u written to global (bf16). Means never touch global.
// ===========================================================================
__global__ __launch_bounds__(256)
void gather_sage_kernel(int nbF, int NF, int NC,
                        const int* __restrict__ offs, const int* __restrict__ bins,
                        ushort_t* __restrict__ uf, ushort_t* __restrict__ uc,
                        const ushort_t* __restrict__ embf, const ushort_t* __restrict__ embc,
                        const ushort_t* __restrict__ wlf, const ushort_t* __restrict__ wrf,
                        const float* __restrict__ blf,
                        const ushort_t* __restrict__ wlc, const ushort_t* __restrict__ wrc,
                        const float* __restrict__ blc,
                        const ushort_t* __restrict__ W1) {
    __shared__ short A[64][264];
    bool isF = (int)blockIdx.x < nbF;
    int nrows = isF ? NF : NC;
    int rbase = (isF ? blockIdx.x : blockIdx.x - nbF) * 64;
    ushort_t* uo = isF ? uf : uc;
    const ushort_t* embS = isF ? embf : embc;   // self features
    const ushort_t* embN = isF ? embc : embf;   // neighbor (src) features
    const ushort_t* Wl = isF ? wlf : wlc;
    const ushort_t* Wr = isF ? wrf : wrc;
    const float* bl = isF ? blf : blc;
    int goff = isF ? 0 : NF;
    int koff = isF ? 128 : 0;

    int tid = threadIdx.x;
    int lane = tid & 63;
    int wv = tid >> 6;
    int l15 = lane & 15;
    int quad = lane >> 4;
    int col8 = l15 * 8;
    int nb0 = 32 * wv + l15;

    // ---- Phase A: gather means (wave wv owns rows wv*16 .. wv*16+15) ----
    for (int rr = 0; rr < 16; ++rr) {
        int r = wv * 16 + rr;
        int row = rbase + r;
        float acc[8];
        #pragma unroll
        for (int t = 0; t < 8; ++t) acc[t] = 0.f;
        int deg = 0;
        if (row < nrows) {
            int g = goff + row;
            int start = offs[g];
            int end = offs[g + 1];
            deg = end - start;
            int nPre = deg < 64 ? deg : 64;
            int pre = (lane < nPre) ? bins[start + lane] : 0;
            for (int it = 0; it < (nPre + 7) / 8; ++it) {
                int e0 = 8 * it + quad;
                int e1 = e0 + 4;
                int s0 = __shfl(pre, e0, 64);
                int s1 = __shfl(pre, e1, 64);
                if (e0 < nPre) {
                    uint4 rv = *(const uint4*)(embN + (size_t)s0 * H + col8);
                    acc[0] += bflo(rv.x); acc[1] += bfhi(rv.x);
                    acc[2] += bflo(rv.y); acc[3] += bfhi(rv.y);
                    acc[4] += bflo(rv.z); acc[5] += bfhi(rv.z);
                    acc[6] += bflo(rv.w); acc[7] += bfhi(rv.w);
                }
                if (e1 < nPre) {
                    uint4 rv = *(const uint4*)(embN + (size_t)s1 * H + col8);
                    acc[0] += bflo(rv.x); acc[1] += bfhi(rv.x);
                    acc[2] += bflo(rv.y); acc[3] += bfhi(rv.y);
                    acc[4] += bflo(rv.z); acc[5] += bfhi(rv.z);
                    acc[6] += bflo(rv.w); acc[7] += bfhi(rv.w);
                }
            }
            for (int k = start + 64 + quad; k < end; k += 4) {
                int s = bins[k];
                uint4 rv = *(const uint4*)(embN + (size_t)s * H + col8);
                acc[0] += bflo(rv.x); acc[1] += bfhi(rv.x);
                acc[2] += bflo(rv.y); acc[3] += bfhi(rv.y);
                acc[4] += bflo(rv.z); acc[5] += bfhi(rv.z);
                acc[6] += bflo(rv.w); acc[7] += bfhi(rv.w);
            }
        }
        #pragma unroll
        for (int t = 0; t < 8; ++t) {
            acc[t] += __shfl_xor(acc[t], 16, 64);
            acc[t] += __shfl_xor(acc[t], 32, 64);
        }
        if (quad == 0) {
            float inv = 1.0f / fmaxf((float)deg, 1.0f);
            short8 o;
            #pragma unroll
            for (int t = 0; t < 8; ++t) o[t] = f2bf(acc[t] * inv);
            *(short8*)&A[r][col8] = o;
        }
    }

    // ---- Phase B: stage self emb into cols 128..255 ----
    for (int idx = tid; idx < 64 * 32; idx += 256) {
        int r = idx >> 5, qq = idx & 31;
        int row = rbase + r;
        short4v s = (short4v){0, 0, 0, 0};
        if (row < nrows) s = *(const short4v*)(embS + (size_t)row * H + qq * 4);
        *(short4v*)&A[r][128 + qq * 4] = s;
    }

    floatx4 acc[4][2];
    #pragma unroll
    for (int i = 0; i < 4; ++i)
        #pragma unroll
        for (int j = 0; j < 2; ++j)
            acc[i][j] = (floatx4){0.f, 0.f, 0.f, 0.f};

    float blv0 = bl[nb0];
    float blv1 = bl[nb0 + 16];
    __syncthreads();

    // ---- GEMM1: K=256 (mean@Wl^T | emb@Wr^T) ----
    #pragma unroll
    for (int half = 0; half < 2; ++half) {
        const ushort_t* W = half ? Wr : Wl;
        #pragma unroll
        for (int ks = 0; ks < 4; ++ks) {
            int kb = ks * 32 + quad * 8;
            short8 b0 = *(const short8*)(W + (size_t)nb0 * H + kb);
            short8 b1 = *(const short8*)(W + (size_t)(nb0 + 16) * H + kb);
            int ka = half * 128 + kb;
            #pragma unroll
            for (int mt = 0; mt < 4; ++mt) {
                short8 a = *(const short8*)&A[16 * mt + l15][ka];
                acc[mt][0] = __builtin_amdgcn_mfma_f32_16x16x32_bf16(a, b0, acc[mt][0], 0, 0, 0);
                acc[mt][1] = __builtin_amdgcn_mfma_f32_16x16x32_bf16(a, b1, acc[mt][1], 0, 0, 0);
            }
        }
    }

    // ---- relu(acc + bl) -> LDS (A-operand layout, cols 0..127) ----
    __syncthreads();
    #pragma unroll
    for (int mt = 0; mt < 4; ++mt)
        #pragma unroll
        for (int nt = 0; nt < 2; ++nt) {
            float blv = nt ? blv1 : blv0;
            int colw = nb0 + 16 * nt;
            #pragma unroll
            for (int rg = 0; rg < 4; ++rg) {
                int row = 16 * mt + quad * 4 + rg;
                A[row][colw] = f2bf(fmaxf(acc[mt][nt][rg] + blv, 0.0f));
                acc[mt][nt][rg] = 0.0f;
            }
        }
    __syncthreads();

    // ---- GEMM2: u = upd @ W1part^T (K=128) ----
    const ushort_t* W1p = W1 + koff;
    #pragma unroll
    for (int ks = 0; ks < 4; ++ks) {
        int kb = ks * 32 + quad * 8;
        short8 b0 = *(const short8*)(W1p + (size_t)nb0 * 256 + kb);
        short8 b1 = *(const short8*)(W1p + (size_t)(nb0 + 16) * 256 + kb);
        #pragma unroll
        for (int mt = 0; mt < 4; ++mt) {
            short8 a = *(const short8*)&A[16 * mt + l15][kb];
            acc[mt][0] = __builtin_amdgcn_mfma_f32_16x16x32_bf16(a, b0, acc[mt][0], 0, 0, 0);
            acc[mt][1] = __builtin_amdgcn_mfma_f32_16x16x32_bf16(a, b1, acc[mt][1], 0, 0, 0);
        }
    }

    // ---- write u (bf16) ----
    #pragma unroll
    for (int mt = 0; mt < 4; ++mt)
        #pragma unroll
        for (int rg = 0; rg < 4; ++rg) {
            int row = rbase + 16 * mt + quad * 4 + rg;
            if (row < nrows) {
                uo[(size_t)row * H + nb0]      = (ushort_t)f2bf(acc[mt][0][rg]);
                uo[(size_t)row * H + nb0 + 16] = (ushort_t)f2bf(acc[mt][1][rg]);
            }
        }
}

// ===========================================================================
// Fallback CSR kernels (R6 path) + standalone gather/sage — only if ws small.
// ===========================================================================
__global__ __launch_bounds__(256)
void hist2_kernel(const int* __restrict__ ei1, const int* __restrict__ ei2, int E,
                  int* __restrict__ deg1, int* __restrict__ deg2) {
    int t = blockIdx.x * 256 + threadIdx.x;
    if (t < E) atomicAdd(&deg1[ei1[E + t]], 1);
    else if (t < 2 * E) { int e = t - E; atomicAdd(&deg2[ei2[E + e]], 1); }
}

__global__ __launch_bounds__(256)
void scan_blocksum_kernel(const int* __restrict__ deg, int n, int* __restrict__ bsums) {
    __shared__ int sdata[256];
    int tid = threadIdx.x;
    int base = blockIdx.x * 1024 + tid * 4;
    int v = 0;
    #pragma unroll
    for (int i = 0; i < 4; ++i) { int idx = base + i; if (idx < n) v += deg[idx]; }
    sdata[tid] = v;
    __syncthreads();
    for (int off = 128; off > 0; off >>= 1) {
        if (tid < off) sdata[tid] += sdata[tid + off];
        __syncthreads();
    }
    if (tid == 0) bsums[blockIdx.x] = sdata[0];
}

__global__ __launch_bounds__(256)
void scan_write_kernel(int* __restrict__ data, int n, const int* __restrict__ bsums) {
    __shared__ int sdata[256];
    __shared__ int boff;
    int tid = threadIdx.x;
    if (tid < 64) {
        int acc = 0;
        for (int i = tid; i < (int)blockIdx.x; i += 64) acc += bsums[i];
        #pragma unroll
        for (int off = 32; off > 0; off >>= 1) acc += __shfl_xor(acc, off, 64);
        if (tid == 0) boff = acc;
    }
    int base = blockIdx.x * 1024 + tid * 4;
    int v[4]; int s = 0;
    #pragma unroll
    for (int i = 0; i < 4; ++i) { int idx = base + i; v[i] = (idx < n) ? data[idx] : 0; s += v[i]; }
    sdata[tid] = s;
    __syncthreads();
    for (int off = 1; off < 256; off <<= 1) {
        int t = (tid >= off) ? sdata[tid - off] : 0;
        __syncthreads();
        sdata[tid] += t;
        __syncthreads();
    }
    int excl = (tid == 0 ? 0 : sdata[tid - 1]) + boff;
    #pragma unroll
    for (int i = 0; i < 4; ++i) {
        int idx = base + i;
        if (idx < n) data[idx] = excl;
        excl += v[i];
    }
}

// converts inclusive-end offsets (post-bin2 state) to start-array semantics
__global__ __launch_bounds__(256)
void incl_to_start_kernel(const int* __restrict__ incl, int nTot, int* __restrict__ offs) {
    int g = blockIdx.x * 256 + threadIdx.x;
    if (g < nTot) offs[g + 1] = incl[g];
    if (g == 0) offs[0] = 0;
}

__global__ __launch_bounds__(256)
void bin2_kernel(const int* __restrict__ ei1, const int* __restrict__ ei2, int E,
                 int* __restrict__ offs1, int* __restrict__ offs2,
                 int* __restrict__ bins) {
    int t = blockIdx.x * 256 + threadIdx.x;
    if (t < E) {
        int pos = atomicAdd(&offs1[ei1[E + t]], 1);
        bins[pos] = ei1[t];
    } else if (t < 2 * E) {
        int e = t - E;
        int pos = atomicAdd(&offs2[ei2[E + e]], 1);
        bins[pos] = ei2[e];
    }
}

// ===========================================================================
// Classifier: 16 lanes per pair (4 pairs/wave).
// ===========================================================================
__global__ __launch_bounds__(256)
void classify_kernel(const int* __restrict__ eli, int L,
                     const ushort_t* __restrict__ u_can,
                     const ushort_t* __restrict__ u_flag,
                     const float* __restrict__ b1,
                     const float* __restrict__ W2,
                     const float* __restrict__ b2,
                     float* __restrict__ out) {
    int tid = threadIdx.x;
    int lane = tid & 63;
    int wv = tid >> 6;
    int sub = lane >> 4;
    int l15 = lane & 15;
    int p = blockIdx.x * 16 + wv * 4 + sub;
    if (p >= L) return;
    int i = eli[p];
    int j = eli[L + p];
    uint4 a = ((const uint4*)(u_can  + (size_t)i * H))[l15];
    uint4 b = ((const uint4*)(u_flag + (size_t)j * H))[l15];
    float4 bb0 = ((const float4*)b1)[l15 * 2];
    float4 bb1 = ((const float4*)b1)[l15 * 2 + 1];
    float4 w0  = ((const float4*)W2)[l15 * 2];
    float4 w1  = ((const float4*)W2)[l15 * 2 + 1];
    float s = fmaxf(bflo(a.x) + bflo(b.x) + bb0.x, 0.f) * w0.x
            + fmaxf(bfhi(a.x) + bfhi(b.x) + bb0.y, 0.f) * w0.y
            + fmaxf(bflo(a.y) + bflo(b.y) + bb0.z, 0.f) * w0.z
            + fmaxf(bfhi(a.y) + bfhi(b.y) + bb0.w, 0.f) * w0.w
            + fmaxf(bflo(a.z) + bflo(b.z) + bb1.x, 0.f) * w1.x
            + fmaxf(bfhi(a.z) + bfhi(b.z) + bb1.y, 0.f) * w1.y
            + fmaxf(bflo(a.w) + bflo(b.w) + bb1.z, 0.f) * w1.z
            + fmaxf(bfhi(a.w) + bfhi(b.w) + bb1.w, 0.f) * w1.w;
    #pragma unroll
    for (int off = 8; off > 0; off >>= 1)
        s += __shfl_down(s, off, 16);
    if (l15 == 0) out[p] = s + b2[0];
}

// ===========================================================================
extern "C" void kernel_launch(void* const* d_in, const int* in_sizes, int n_in,
                              void* d_out, int out_size, void* d_ws, size_t ws_size,
                              hipStream_t stream) {
    const int*   ei_cf    = (const int*)d_in[2];
    const int*   ei_fc    = (const int*)d_in[3];
    const int*   eli      = (const int*)d_in[4];
    const float* can_emb  = (const float*)d_in[5];
    const float* flag_emb = (const float*)d_in[6];
    const float* Wl_cf    = (const float*)d_in[7];
    const float* bl_cf    = (const float*)d_in[8];
    const float* Wr_cf    = (const float*)d_in[9];
    const float* Wl_fc    = (const float*)d_in[10];
    const float* bl_fc    = (const float*)d_in[11];
    const float* Wr_fc    = (const float*)d_in[12];
    const float* W1       = (const float*)d_in[13];
    const float* b1       = (const float*)d_in[14];
    const float* W2       = (const float*)d_in[15];
    const float* b2       = (const float*)d_in[16];
    float* out = (float*)d_out;

    const int NCAN  = in_sizes[0];
    const int NFLAG = in_sizes[1];
    const int E     = in_sizes[2] / 2;
    const int L     = in_sizes[4] / 2;
    const int nTot  = NCAN + NFLAG;
    const int B     = (nTot + 255) >> BSH;

    // common bf16 buffers: u_can | u_flag | embc | embf
    ushort_t* uc   = (ushort_t*)d_ws;                         // NCAN*H
    ushort_t* uf   = uc + (size_t)NCAN * H;                   // NFLAG*H
    ushort_t* embc = uf + (size_t)NFLAG * H;                  // NCAN*H
    ushort_t* embf = embc + (size_t)NCAN * H;                 // NFLAG*H
    char* tail = (char*)(embf + (size_t)NFLAG * H);
    size_t tail_off = (size_t)(tail - (char*)d_ws);

    int nbF = (NFLAG + 63) / 64, nbC = (NCAN + 63) / 64;
    int n4c = NCAN * H / 4, n4f = NFLAG * H / 4;
    int nbcvt = (n4c + n4f + 24576 + 255) / 256;

    // tail: offs[nTot+1] | bcnt[MAXB] | bbase[MAXB+1] | bfront[MAXB] | bins[2E] | part[2E] | wb
    size_t off_offs  = tail_off;
    size_t off_bcnt  = off_offs  + (size_t)(nTot + 1) * 4;
    size_t off_bbase = off_bcnt  + (size_t)MAXB * 4;
    size_t off_bfrnt = off_bbase + (size_t)(MAXB + 1) * 4;
    size_t off_bins  = off_bfrnt + (size_t)MAXB * 4;
    size_t off_part  = (off_bins + (size_t)2 * E * 4 + 7) & ~(size_t)7;
    size_t off_wb    = off_part + (size_t)2 * E * 8;
    size_t need_new  = off_wb + 98304 * 2;

    int* offs   = (int*)((char*)d_ws + off_offs);
    int* bcnt   = (int*)((char*)d_ws + off_bcnt);
    int* bbase  = (int*)((char*)d_ws + off_bbase);
    int* bfront = (int*)((char*)d_ws + off_bfrnt);
    int* bins   = (int*)((char*)d_ws + off_bins);

    if (ws_size >= need_new && B <= MAXB) {
        uint2* part = (uint2*)((char*)d_ws + off_part);
        ushort_t* wb = (ushort_t*)((char*)d_ws + off_wb);
        ushort_t* wb_wlcf = wb, *wb_wrcf = wb + 16384, *wb_wlfc = wb + 32768,
                 *wb_wrfc = wb + 49152, *wb_w1 = wb + 65536;

        int nbh = (2 * E + 4095) >> 12;
        hipMemsetAsync(bcnt, 0, (size_t)MAXB * 4, stream);
        bucket_hist_cvt_kernel<<<nbh + nbcvt, 256, 0, stream>>>(
            ei_cf, ei_fc, E, NFLAG, B, bcnt, nbh,
            can_emb, n4c, flag_emb, n4f, embc, embf,
            Wl_cf, Wr_cf, Wl_fc, Wr_fc, W1, wb);
        bucket_scan_kernel<<<1, 256, 0, stream>>>(bcnt, B, bbase, bfront);
        partition_kernel<<<nbh, 256, 0, stream>>>(ei_cf, ei_fc, E, NFLAG, B, bfront, part);
        fine_bin_kernel<<<B, 256, 0, stream>>>(bbase, nTot, part, offs, bins);
        gather_sage_kernel<<<nbF + nbC, 256, 0, stream>>>(
            nbF, NFLAG, NCAN, offs, bins, uf, uc, embf, embc,
            wb_wlcf, wb_wrcf, bl_cf, wb_wlfc, wb_wrfc, bl_fc, wb_w1);
    } else {
        // fallback: R6-style CSR build (scattered bin2) + incl->start fixup,
        // then the same fused gather_sage kernel.
        int* scanf_ = bins;                        // reuse region: NFLAG
        int* scanc_ = scanf_ + NFLAG;              // NCAN
        int* bins2  = scanc_ + NCAN;               // 2E
        int* bsums  = bins2 + 2 * E;               // 256
        ushort_t* wb = (ushort_t*)(bsums + 256);
        ushort_t* wb_wlcf = wb, *wb_wrcf = wb + 16384, *wb_wlfc = wb + 32768,
                 *wb_wrfc = wb + 49152, *wb_w1 = wb + 65536;

        bucket_hist_cvt_kernel<<<nbcvt, 256, 0, stream>>>(
            ei_cf, ei_fc, E, NFLAG, B, bcnt, 0,
            can_emb, n4c, flag_emb, n4f, embc, embf,
            Wl_cf, Wr_cf, Wl_fc, Wr_fc, W1, wb);
        hipMemsetAsync(scanf_, 0, ((size_t)NFLAG + NCAN) * 4, stream);
        int nb = (nTot + 1023) / 1024;
        hist2_kernel<<<(2 * E + 255) / 256, 256, 0, stream>>>(ei_cf, ei_fc, E, scanf_, scanc_);
        scan_blocksum_kernel<<<nb, 256, 0, stream>>>(scanf_, nTot, bsums);
        scan_write_kernel<<<nb, 256, 0, stream>>>(scanf_, nTot, bsums);
        bin2_kernel<<<(2 * E + 255) / 256, 256, 0, stream>>>(ei_cf, ei_fc, E, scanf_, scanc_, bins2);
        incl_to_start_kernel<<<(nTot + 255) / 256, 256, 0, stream>>>(scanf_, nTot, offs);
        gather_sage_kernel<<<nbF + nbC, 256, 0, stream>>>(
            nbF, NFLAG, NCAN, offs, bins2, uf, uc, embf, embc,
            wb_wlcf, wb_wrcf, bl_cf, wb_wlfc, wb_wrfc, bl_fc, wb_w1);
    }

    classify_kernel<<<(L + 15) / 16, 256, 0, stream>>>(
        eli, L, uc, uf, b1, W2, b2, out);
}

// Round 9
// 341.113 us; speedup vs baseline: 1.0462x; 1.0462x over previous
//
#include <hip/hip_runtime.h>
#include <hip/hip_bf16.h>

#define H 128
#define BSH 8              // 256 nodes per coarse bucket
#define MAXB 1024          // max buckets (nTot <= 262144)

typedef __attribute__((ext_vector_type(8))) short short8;
typedef __attribute__((ext_vector_type(4))) short short4v;
typedef __attribute__((ext_vector_type(4))) float floatx4;
typedef unsigned short ushort_t;
typedef unsigned int uint_t;

__device__ __forceinline__ short f2bf(float f) {
    __hip_bfloat16 h = __float2bfloat16(f);
    return *reinterpret_cast<short*>(&h);
}
__device__ __forceinline__ float bflo(uint_t u) { return __uint_as_float(u << 16); }
__device__ __forceinline__ float bfhi(uint_t u) { return __uint_as_float(u & 0xFFFF0000u); }
__device__ __forceinline__ uint_t pack_bf2(float x, float y) {
    return (uint_t)(ushort_t)f2bf(x) | ((uint_t)(ushort_t)f2bf(y) << 16);
}

// ===========================================================================
// Coarse bucket histogram (LDS) + fused fp32->bf16 converts (emb + weights).
// ===========================================================================
__global__ __launch_bounds__(256)
void bucket_hist_cvt_kernel(const int* __restrict__ ei1, const int* __restrict__ ei2,
                            int E, int NF, int B, int* __restrict__ bcnt, int nbh,
                            const float* __restrict__ a, int n4a,
                            const float* __restrict__ b, int n4b,
                            ushort_t* __restrict__ da, ushort_t* __restrict__ db,
                            const float* __restrict__ Wl_cf, const float* __restrict__ Wr_cf,
                            const float* __restrict__ Wl_fc, const float* __restrict__ Wr_fc,
                            const float* __restrict__ W1, ushort_t* __restrict__ wb) {
    __shared__ int h[MAXB];
    int tid = threadIdx.x;
    if ((int)blockIdx.x < nbh) {
        for (int i = tid; i < B; i += 256) h[i] = 0;
        __syncthreads();
        int base = blockIdx.x * 4096;
        #pragma unroll 4
        for (int it = 0; it < 16; ++it) {
            int t = base + it * 256 + tid;
            if (t < 2 * E) {
                int g = (t < E) ? ei1[E + t] : (ei2[E + t - E] + NF);
                atomicAdd(&h[g >> BSH], 1);
            }
        }
        __syncthreads();
        for (int i = tid; i < B; i += 256)
            if (h[i]) atomicAdd(&bcnt[i], h[i]);
        return;
    }
    // ---- cvt part ----
    int i = ((int)blockIdx.x - nbh) * 256 + tid;
    const float* src; ushort_t* dst; int k;
    if (i < n4a) { src = a; dst = da; k = i; }
    else if (i < n4a + n4b) { src = b; dst = db; k = i - n4a; }
    else {
        int idx = (i - n4a - n4b) * 4;
        if (idx >= 98304) return;
        int off;
        if      (idx < 16384) { src = Wl_cf; off = idx; }
        else if (idx < 32768) { src = Wr_cf; off = idx - 16384; }
        else if (idx < 49152) { src = Wl_fc; off = idx - 32768; }
        else if (idx < 65536) { src = Wr_fc; off = idx - 49152; }
        else                  { src = W1;    off = idx - 65536; }
        float4 v = *(const float4*)(src + off);
        short4v s;
        s[0] = f2bf(v.x); s[1] = f2bf(v.y); s[2] = f2bf(v.z); s[3] = f2bf(v.w);
        *(short4v*)(wb + idx) = s;
        return;
    }
    float4 v = ((const float4*)src)[k];
    short4v s;
    s[0] = f2bf(v.x); s[1] = f2bf(v.y); s[2] = f2bf(v.z); s[3] = f2bf(v.w);
    ((short4v*)dst)[k] = s;
}

// ===========================================================================
// Partition: bucket-sorted packed entries (local<<24 | src), line-local
// writes. Bucket bases recomputed locally (kills the 1-block scan launch);
// bfront is a zero-initialized RELATIVE counter per bucket.
// ===========================================================================
__global__ __launch_bounds__(256)
void partition_kernel(const int* __restrict__ ei1, const int* __restrict__ ei2,
                      int E, int NF, int B, const int* __restrict__ bcnt,
                      int* __restrict__ bfront, uint_t* __restrict__ part) {
    __shared__ int h[MAXB];
    __shared__ int basex[MAXB];
    __shared__ int sdata[256];
    int tid = threadIdx.x;
    // local exclusive scan of bcnt -> basex (global bucket bases)
    {
        int base4 = tid * 4;
        int v[4]; int s = 0;
        #pragma unroll
        for (int i = 0; i < 4; ++i) { int idx = base4 + i; v[i] = (idx < B) ? bcnt[idx] : 0; s += v[i]; }
        sdata[tid] = s;
        __syncthreads();
        for (int off = 1; off < 256; off <<= 1) {
            int t = (tid >= off) ? sdata[tid - off] : 0;
            __syncthreads();
            sdata[tid] += t;
            __syncthreads();
        }
        int excl = tid ? sdata[tid - 1] : 0;
        #pragma unroll
        for (int i = 0; i < 4; ++i) {
            int idx = base4 + i;
            if (idx < B) basex[idx] = excl;
            excl += v[i];
        }
    }
    for (int i = tid; i < B; i += 256) h[i] = 0;
    __syncthreads();
    int base = blockIdx.x * 4096;
    #pragma unroll 4
    for (int it = 0; it < 16; ++it) {
        int t = base + it * 256 + tid;
        if (t < 2 * E) {
            int g = (t < E) ? ei1[E + t] : (ei2[E + t - E] + NF);
            atomicAdd(&h[g >> BSH], 1);
        }
    }
    __syncthreads();
    for (int i = tid; i < B; i += 256) {
        int c = h[i];
        if (c) basex[i] += atomicAdd(&bfront[i], c);   // reserve block's range
    }
    __syncthreads();
    for (int i = tid; i < B; i += 256) h[i] = 0;
    __syncthreads();
    #pragma unroll 4
    for (int it = 0; it < 16; ++it) {
        int t = base + it * 256 + tid;
        if (t < 2 * E) {
            int g, s;
            if (t < E) { g = ei1[E + t]; s = ei1[t]; }
            else       { int e = t - E; g = ei2[E + e] + NF; s = ei2[e]; }
            int bk = g >> BSH;
            int r = atomicAdd(&h[bk], 1);
            part[basex[bk] + r] = ((uint_t)(g & 255) << 24) | (uint_t)s;
        }
    }
}

// ===========================================================================
// Fine bin: one block per bucket; seg bounds from a local reduction over
// bcnt[0..b). LDS 256-hist + scan -> CSR start offsets + line-local bins.
// ===========================================================================
__global__ __launch_bounds__(256)
void fine_bin_kernel(const int* __restrict__ bcnt, int B, int nTot, int E2,
                     const uint_t* __restrict__ part,
                     int* __restrict__ offs, int* __restrict__ bins) {
    __shared__ int cnt[256];
    __shared__ int sdata[256];
    __shared__ int excl[256];
    int b = blockIdx.x;
    int tid = threadIdx.x;
    // seg0 = sum bcnt[0..b)
    {
        int partial = 0;
        for (int i = tid; i < b; i += 256) partial += bcnt[i];
        sdata[tid] = partial;
        __syncthreads();
        for (int off = 128; off > 0; off >>= 1) {
            if (tid < off) sdata[tid] += sdata[tid + off];
            __syncthreads();
        }
    }
    int seg0 = sdata[0];
    int seg1 = seg0 + bcnt[b];
    int gbase = b << BSH;
    __syncthreads();
    cnt[tid] = 0;
    __syncthreads();
    for (int k = seg0 + tid; k < seg1; k += 256)
        atomicAdd(&cnt[part[k] >> 24], 1);
    __syncthreads();
    sdata[tid] = cnt[tid];
    __syncthreads();
    for (int off = 1; off < 256; off <<= 1) {
        int t = (tid >= off) ? sdata[tid - off] : 0;
        __syncthreads();
        sdata[tid] += t;
        __syncthreads();
    }
    excl[tid] = tid ? sdata[tid - 1] : 0;
    int g = gbase + tid;
    if (g < nTot) offs[g] = seg0 + excl[tid];
    if (b == 0 && tid == 0) offs[nTot] = E2;
    cnt[tid] = 0;
    __syncthreads();
    for (int k = seg0 + tid; k < seg1; k += 256) {
        uint_t e = part[k];
        int l = (int)(e >> 24);
        int r = atomicAdd(&cnt[l], 1);
        bins[seg0 + excl[l] + r] = (int)(e & 0x00FFFFFFu);
    }
}

// ===========================================================================
// Gather-mean: one wave per dst node; quarter q x uint4 -> one load = 4 rows.
// Start-array offsets: start = offs[g], end = offs[g+1].
// ===========================================================================
__global__ __launch_bounds__(256)
void gather_mean3_kernel(const int* __restrict__ offs, int nTotal, int split,
                         const int* __restrict__ bins,
                         const ushort_t* __restrict__ embA, ushort_t* __restrict__ aggA,
                         const ushort_t* __restrict__ embB, ushort_t* __restrict__ aggB) {
    int g = blockIdx.x * 4 + (threadIdx.x >> 6);
    if (g >= nTotal) return;
    int lane = threadIdx.x & 63;
    int q = lane >> 4, l15 = lane & 15;
    int start = offs[g];
    int end = offs[g + 1];
    int deg = end - start;
    const ushort_t* emb; ushort_t* agg; int row;
    if (g < split) { emb = embA; agg = aggA; row = g; }
    else           { emb = embB; agg = aggB; row = g - split; }

    float acc[8];
    #pragma unroll
    for (int t = 0; t < 8; ++t) acc[t] = 0.f;

    int nPre = deg < 64 ? deg : 64;
    int pre = (lane < nPre) ? bins[start + lane] : 0;

    int col = l15 * 8;
    for (int it = 0; it < (nPre + 7) / 8; ++it) {
        int e0 = 8 * it + q;
        int e1 = e0 + 4;
        int s0 = __shfl(pre, e0, 64);
        int s1 = __shfl(pre, e1, 64);
        if (e0 < nPre) {
            uint4 r = *(const uint4*)(emb + (size_t)s0 * H + col);
            acc[0] += bflo(r.x); acc[1] += bfhi(r.x);
            acc[2] += bflo(r.y); acc[3] += bfhi(r.y);
            acc[4] += bflo(r.z); acc[5] += bfhi(r.z);
            acc[6] += bflo(r.w); acc[7] += bfhi(r.w);
        }
        if (e1 < nPre) {
            uint4 r = *(const uint4*)(emb + (size_t)s1 * H + col);
            acc[0] += bflo(r.x); acc[1] += bfhi(r.x);
            acc[2] += bflo(r.y); acc[3] += bfhi(r.y);
            acc[4] += bflo(r.z); acc[5] += bfhi(r.z);
            acc[6] += bflo(r.w); acc[7] += bfhi(r.w);
        }
    }
    for (int k = start + 64 + q; k < end; k += 4) {
        int s = bins[k];
        uint4 r = *(const uint4*)(emb + (size_t)s * H + col);
        acc[0] += bflo(r.x); acc[1] += bfhi(r.x);
        acc[2] += bflo(r.y); acc[3] += bfhi(r.y);
        acc[4] += bflo(r.z); acc[5] += bfhi(r.z);
        acc[6] += bflo(r.w); acc[7] += bfhi(r.w);
    }

    #pragma unroll
    for (int t = 0; t < 8; ++t) {
        acc[t] += __shfl_xor(acc[t], 16, 64);
        acc[t] += __shfl_xor(acc[t], 32, 64);
    }
    if (q == 0) {
        float inv = 1.0f / fmaxf((float)deg, 1.0f);
        uint4 o;
        o.x = pack_bf2(acc[0] * inv, acc[1] * inv);
        o.y = pack_bf2(acc[2] * inv, acc[3] * inv);
        o.z = pack_bf2(acc[4] * inv, acc[5] * inv);
        o.w = pack_bf2(acc[6] * inv, acc[7] * inv);
        *(uint4*)(agg + (size_t)row * H + col) = o;
    }
}

// ===========================================================================
// MFMA fused SAGE, both node types in one launch (block < nbF -> flag).
//   upd = relu([mean|emb] @ [Wl|Wr]^T + bl);  io := upd @ W1part^T  (in place)
// ===========================================================================
__global__ __launch_bounds__(256)
void sage2_kernel(int nbF, int NF, int NC,
                  ushort_t* __restrict__ aggf, const ushort_t* __restrict__ embf,
                  ushort_t* __restrict__ aggc, const ushort_t* __restrict__ embc,
                  const ushort_t* __restrict__ wlf, const ushort_t* __restrict__ wrf,
                  const float* __restrict__ blf,
                  const ushort_t* __restrict__ wlc, const ushort_t* __restrict__ wrc,
                  const float* __restrict__ blc,
                  const ushort_t* __restrict__ W1) {
    __shared__ short A[64][264];
    bool isF = (int)blockIdx.x < nbF;
    int nrows = isF ? NF : NC;
    int rbase = (isF ? blockIdx.x : blockIdx.x - nbF) * 64;
    ushort_t* io = isF ? aggf : aggc;
    const ushort_t* emb = isF ? embf : embc;
    const ushort_t* Wl = isF ? wlf : wlc;
    const ushort_t* Wr = isF ? wrf : wrc;
    const float* bl = isF ? blf : blc;
    int koff = isF ? 128 : 0;

    int tid = threadIdx.x;
    int lane = tid & 63;
    int wv = tid >> 6;
    int l15 = lane & 15;
    int quad = lane >> 4;
    int nb0 = 32 * wv + l15;

    for (int idx = tid; idx < 64 * 64; idx += 256) {
        int r = idx >> 6, qq = idx & 63;
        int row = rbase + r;
        short4v s = (short4v){0, 0, 0, 0};
        if (row < nrows) {
            const ushort_t* src = (qq < 32) ? (io + (size_t)row * H + qq * 4)
                                            : (emb + (size_t)row * H + (qq - 32) * 4);
            s = *(const short4v*)src;
        }
        *(short4v*)&A[r][qq * 4] = s;
    }

    floatx4 acc[4][2];
    #pragma unroll
    for (int i = 0; i < 4; ++i)
        #pragma unroll
        for (int j = 0; j < 2; ++j)
            acc[i][j] = (floatx4){0.f, 0.f, 0.f, 0.f};

    float blv0 = bl[nb0];
    float blv1 = bl[nb0 + 16];
    __syncthreads();

    #pragma unroll
    for (int half = 0; half < 2; ++half) {
        const ushort_t* W = half ? Wr : Wl;
        #pragma unroll
        for (int ks = 0; ks < 4; ++ks) {
            int kb = ks * 32 + quad * 8;
            short8 b0 = *(const short8*)(W + (size_t)nb0 * H + kb);
            short8 b1 = *(const short8*)(W + (size_t)(nb0 + 16) * H + kb);
            int ka = half * 128 + kb;
            #pragma unroll
            for (int mt = 0; mt < 4; ++mt) {
                short8 a = *(const short8*)&A[16 * mt + l15][ka];
                acc[mt][0] = __builtin_amdgcn_mfma_f32_16x16x32_bf16(a, b0, acc[mt][0], 0, 0, 0);
                acc[mt][1] = __builtin_amdgcn_mfma_f32_16x16x32_bf16(a, b1, acc[mt][1], 0, 0, 0);
            }
        }
    }

    __syncthreads();
    #pragma unroll
    for (int mt = 0; mt < 4; ++mt)
        #pragma unroll
        for (int nt = 0; nt < 2; ++nt) {
            float blv = nt ? blv1 : blv0;
            int colw = nb0 + 16 * nt;
            #pragma unroll
            for (int rg = 0; rg < 4; ++rg) {
                int row = 16 * mt + quad * 4 + rg;
                A[row][colw] = f2bf(fmaxf(acc[mt][nt][rg] + blv, 0.0f));
                acc[mt][nt][rg] = 0.0f;
            }
        }
    __syncthreads();

    const ushort_t* W1p = W1 + koff;
    #pragma unroll
    for (int ks = 0; ks < 4; ++ks) {
        int kb = ks * 32 + quad * 8;
        short8 b0 = *(const short8*)(W1p + (size_t)nb0 * 256 + kb);
        short8 b1 = *(const short8*)(W1p + (size_t)(nb0 + 16) * 256 + kb);
        #pragma unroll
        for (int mt = 0; mt < 4; ++mt) {
            short8 a = *(const short8*)&A[16 * mt + l15][kb];
            acc[mt][0] = __builtin_amdgcn_mfma_f32_16x16x32_bf16(a, b0, acc[mt][0], 0, 0, 0);
            acc[mt][1] = __builtin_amdgcn_mfma_f32_16x16x32_bf16(a, b1, acc[mt][1], 0, 0, 0);
        }
    }

    #pragma unroll
    for (int mt = 0; mt < 4; ++mt)
        #pragma unroll
        for (int rg = 0; rg < 4; ++rg) {
            int row = rbase + 16 * mt + quad * 4 + rg;
            if (row < nrows) {
                io[(size_t)row * H + nb0]      = (ushort_t)f2bf(acc[mt][0][rg]);
                io[(size_t)row * H + nb0 + 16] = (ushort_t)f2bf(acc[mt][1][rg]);
            }
        }
}

// ===========================================================================
// Fallback CSR kernels (scattered bin2 path) — only if ws too small.
// ===========================================================================
__global__ __launch_bounds__(256)
void hist2_kernel(const int* __restrict__ ei1, const int* __restrict__ ei2, int E,
                  int* __restrict__ deg1, int* __restrict__ deg2) {
    int t = blockIdx.x * 256 + threadIdx.x;
    if (t < E) atomicAdd(&deg1[ei1[E + t]], 1);
    else if (t < 2 * E) { int e = t - E; atomicAdd(&deg2[ei2[E + e]], 1); }
}

__global__ __launch_bounds__(256)
void scan_blocksum_kernel(const int* __restrict__ deg, int n, int* __restrict__ bsums) {
    __shared__ int sdata[256];
    int tid = threadIdx.x;
    int base = blockIdx.x * 1024 + tid * 4;
    int v = 0;
    #pragma unroll
    for (int i = 0; i < 4; ++i) { int idx = base + i; if (idx < n) v += deg[idx]; }
    sdata[tid] = v;
    __syncthreads();
    for (int off = 128; off > 0; off >>= 1) {
        if (tid < off) sdata[tid] += sdata[tid + off];
        __syncthreads();
    }
    if (tid == 0) bsums[blockIdx.x] = sdata[0];
}

__global__ __launch_bounds__(256)
void scan_write_kernel(int* __restrict__ data, int n, const int* __restrict__ bsums) {
    __shared__ int sdata[256];
    __shared__ int boff;
    int tid = threadIdx.x;
    if (tid < 64) {
        int acc = 0;
        for (int i = tid; i < (int)blockIdx.x; i += 64) acc += bsums[i];
        #pragma unroll
        for (int off = 32; off > 0; off >>= 1) acc += __shfl_xor(acc, off, 64);
        if (tid == 0) boff = acc;
    }
    int base = blockIdx.x * 1024 + tid * 4;
    int v[4]; int s = 0;
    #pragma unroll
    for (int i = 0; i < 4; ++i) { int idx = base + i; v[i] = (idx < n) ? data[idx] : 0; s += v[i]; }
    sdata[tid] = s;
    __syncthreads();
    for (int off = 1; off < 256; off <<= 1) {
        int t = (tid >= off) ? sdata[tid - off] : 0;
        __syncthreads();
        sdata[tid] += t;
        __syncthreads();
    }
    int excl = (tid == 0 ? 0 : sdata[tid - 1]) + boff;
    #pragma unroll
    for (int i = 0; i < 4; ++i) {
        int idx = base + i;
        if (idx < n) data[idx] = excl;
        excl += v[i];
    }
}

__global__ __launch_bounds__(256)
void incl_to_start_kernel(const int* __restrict__ incl, int nTot, int* __restrict__ offs) {
    int g = blockIdx.x * 256 + threadIdx.x;
    if (g < nTot) offs[g + 1] = incl[g];
    if (g == 0) offs[0] = 0;
}

__global__ __launch_bounds__(256)
void bin2_kernel(const int* __restrict__ ei1, const int* __restrict__ ei2, int E,
                 int* __restrict__ offs1, int* __restrict__ offs2,
                 int* __restrict__ bins) {
    int t = blockIdx.x * 256 + threadIdx.x;
    if (t < E) {
        int pos = atomicAdd(&offs1[ei1[E + t]], 1);
        bins[pos] = ei1[t];
    } else if (t < 2 * E) {
        int e = t - E;
        int pos = atomicAdd(&offs2[ei2[E + e]], 1);
        bins[pos] = ei2[e];
    }
}

// ===========================================================================
// Classifier: 16 lanes per pair (4 pairs/wave).
// ===========================================================================
__global__ __launch_bounds__(256)
void classify_kernel(const int* __restrict__ eli, int L,
                     const ushort_t* __restrict__ u_can,
                     const ushort_t* __restrict__ u_flag,
                     const float* __restrict__ b1,
                     const float* __restrict__ W2,
                     const float* __restrict__ b2,
                     float* __restrict__ out) {
    int tid = threadIdx.x;
    int lane = tid & 63;
    int wv = tid >> 6;
    int sub = lane >> 4;
    int l15 = lane & 15;
    int p = blockIdx.x * 16 + wv * 4 + sub;
    if (p >= L) return;
    int i = eli[p];
    int j = eli[L + p];
    uint4 a = ((const uint4*)(u_can  + (size_t)i * H))[l15];
    uint4 b = ((const uint4*)(u_flag + (size_t)j * H))[l15];
    float4 bb0 = ((const float4*)b1)[l15 * 2];
    float4 bb1 = ((const float4*)b1)[l15 * 2 + 1];
    float4 w0  = ((const float4*)W2)[l15 * 2];
    float4 w1  = ((const float4*)W2)[l15 * 2 + 1];
    float s = fmaxf(bflo(a.x) + bflo(b.x) + bb0.x, 0.f) * w0.x
            + fmaxf(bfhi(a.x) + bfhi(b.x) + bb0.y, 0.f) * w0.y
            + fmaxf(bflo(a.y) + bflo(b.y) + bb0.z, 0.f) * w0.z
            + fmaxf(bfhi(a.y) + bfhi(b.y) + bb0.w, 0.f) * w0.w
            + fmaxf(bflo(a.z) + bflo(b.z) + bb1.x, 0.f) * w1.x
            + fmaxf(bfhi(a.z) + bfhi(b.z) + bb1.y, 0.f) * w1.y
            + fmaxf(bflo(a.w) + bflo(b.w) + bb1.z, 0.f) * w1.z
            + fmaxf(bfhi(a.w) + bfhi(b.w) + bb1.w, 0.f) * w1.w;
    #pragma unroll
    for (int off = 8; off > 0; off >>= 1)
        s += __shfl_down(s, off, 16);
    if (l15 == 0) out[p] = s + b2[0];
}

// ===========================================================================
extern "C" void kernel_launch(void* const* d_in, const int* in_sizes, int n_in,
                              void* d_out, int out_size, void* d_ws, size_t ws_size,
                              hipStream_t stream) {
    const int*   ei_cf    = (const int*)d_in[2];
    const int*   ei_fc    = (const int*)d_in[3];
    const int*   eli      = (const int*)d_in[4];
    const float* can_emb  = (const float*)d_in[5];
    const float* flag_emb = (const float*)d_in[6];
    const float* Wl_cf    = (const float*)d_in[7];
    const float* bl_cf    = (const float*)d_in[8];
    const float* Wr_cf    = (const float*)d_in[9];
    const float* Wl_fc    = (const float*)d_in[10];
    const float* bl_fc    = (const float*)d_in[11];
    const float* Wr_fc    = (const float*)d_in[12];
    const float* W1       = (const float*)d_in[13];
    const float* b1       = (const float*)d_in[14];
    const float* W2       = (const float*)d_in[15];
    const float* b2       = (const float*)d_in[16];
    float* out = (float*)d_out;

    const int NCAN  = in_sizes[0];
    const int NFLAG = in_sizes[1];
    const int E     = in_sizes[2] / 2;
    const int L     = in_sizes[4] / 2;
    const int nTot  = NCAN + NFLAG;
    const int B     = (nTot + 255) >> BSH;

    // common bf16 buffers: agg/u (in-place) + emb copies
    ushort_t* aggc = (ushort_t*)d_ws;                         // NCAN*H
    ushort_t* aggf = aggc + (size_t)NCAN * H;                 // NFLAG*H
    ushort_t* embc = aggf + (size_t)NFLAG * H;                // NCAN*H
    ushort_t* embf = embc + (size_t)NCAN * H;                 // NFLAG*H
    char* tail = (char*)(embf + (size_t)NFLAG * H);
    size_t tail_off = (size_t)(tail - (char*)d_ws);

    int nbF = (NFLAG + 63) / 64, nbC = (NCAN + 63) / 64;
    int n4c = NCAN * H / 4, n4f = NFLAG * H / 4;
    int nbcvt = (n4c + n4f + 24576 + 255) / 256;

    // tail: offs[nTot+1] | bcnt[MAXB] | bfront[MAXB] (contig, one memset) |
    //       bins[2E] | part[2E] (uint, 4B) | wb
    size_t off_offs  = tail_off;
    size_t off_bcnt  = off_offs  + (size_t)(nTot + 1) * 4;
    size_t off_bfrnt = off_bcnt  + (size_t)MAXB * 4;
    size_t off_bins  = off_bfrnt + (size_t)MAXB * 4;
    size_t off_part  = off_bins  + (size_t)2 * E * 4;
    size_t off_wb    = off_part  + (size_t)2 * E * 4;
    size_t need_new  = off_wb + 98304 * 2;

    int* offs   = (int*)((char*)d_ws + off_offs);
    int* bcnt   = (int*)((char*)d_ws + off_bcnt);
    int* bfront = (int*)((char*)d_ws + off_bfrnt);
    int* bins   = (int*)((char*)d_ws + off_bins);

    if (ws_size >= need_new && B <= MAXB) {
        uint_t* part = (uint_t*)((char*)d_ws + off_part);
        ushort_t* wb = (ushort_t*)((char*)d_ws + off_wb);
        ushort_t* wb_wlcf = wb, *wb_wrcf = wb + 16384, *wb_wlfc = wb + 32768,
                 *wb_wrfc = wb + 49152, *wb_w1 = wb + 65536;

        int nbh = (2 * E + 4095) >> 12;
        hipMemsetAsync(bcnt, 0, (size_t)2 * MAXB * 4, stream);   // bcnt + bfront
        bucket_hist_cvt_kernel<<<nbh + nbcvt, 256, 0, stream>>>(
            ei_cf, ei_fc, E, NFLAG, B, bcnt, nbh,
            can_emb, n4c, flag_emb, n4f, embc, embf,
            Wl_cf, Wr_cf, Wl_fc, Wr_fc, W1, wb);
        partition_kernel<<<nbh, 256, 0, stream>>>(ei_cf, ei_fc, E, NFLAG, B, bcnt, bfront, part);
        fine_bin_kernel<<<B, 256, 0, stream>>>(bcnt, B, nTot, 2 * E, part, offs, bins);
        gather_mean3_kernel<<<(nTot + 3) / 4, 256, 0, stream>>>(
            offs, nTot, NFLAG, bins, embc, aggf, embf, aggc);
        sage2_kernel<<<nbF + nbC, 256, 0, stream>>>(
            nbF, NFLAG, NCAN, aggf, embf, aggc, embc,
            wb_wlcf, wb_wrcf, bl_cf, wb_wlfc, wb_wrfc, bl_fc, wb_w1);
    } else {
        // fallback: scattered bin2 CSR + incl->start fixup, then same kernels
        int* scanf_ = bins;                        // NFLAG
        int* scanc_ = scanf_ + NFLAG;              // NCAN
        int* bins2  = scanc_ + NCAN;               // 2E
        int* bsums  = bins2 + 2 * E;               // 256
        ushort_t* wb = (ushort_t*)(bsums + 256);
        ushort_t* wb_wlcf = wb, *wb_wrcf = wb + 16384, *wb_wlfc = wb + 32768,
                 *wb_wrfc = wb + 49152, *wb_w1 = wb + 65536;

        bucket_hist_cvt_kernel<<<nbcvt, 256, 0, stream>>>(
            ei_cf, ei_fc, E, NFLAG, B, bcnt, 0,
            can_emb, n4c, flag_emb, n4f, embc, embf,
            Wl_cf, Wr_cf, Wl_fc, Wr_fc, W1, wb);
        hipMemsetAsync(scanf_, 0, ((size_t)NFLAG + NCAN) * 4, stream);
        int nb = (nTot + 1023) / 1024;
        hist2_kernel<<<(2 * E + 255) / 256, 256, 0, stream>>>(ei_cf, ei_fc, E, scanf_, scanc_);
        scan_blocksum_kernel<<<nb, 256, 0, stream>>>(scanf_, nTot, bsums);
        scan_write_kernel<<<nb, 256, 0, stream>>>(scanf_, nTot, bsums);
        bin2_kernel<<<(2 * E + 255) / 256, 256, 0, stream>>>(ei_cf, ei_fc, E, scanf_, scanc_, bins2);
        incl_to_start_kernel<<<(nTot + 255) / 256, 256, 0, stream>>>(scanf_, nTot, offs);
        gather_mean3_kernel<<<(nTot + 3) / 4, 256, 0, stream>>>(
            offs, nTot, NFLAG, bins2, embc, aggf, embf, aggc);
        sage2_kernel<<<nbF + nbC, 256, 0, stream>>>(
            nbF, NFLAG, NCAN, aggf, embf, aggc, embc,
            wb_wlcf, wb_wrcf, bl_cf, wb_wlfc, wb_wrfc, bl_fc, wb_w1);
    }

    classify_kernel<<<(L + 15) / 16, 256, 0, stream>>>(
        eli, L, aggc, aggf, b1, W2, b2, out);
}